// Round 4
// baseline (236.928 us; speedup 1.0000x reference)
//
#include <hip/hip_runtime.h>
#include <hip/hip_bf16.h>

// Problem constants
#define NN 128
#define CC 64
#define TT 128
#define VV 25
#define RR 8
#define HH 12
#define RELP 28        // padded v-stride of rel rows (16B-aligned quads)
#define RELR (VV*RELP)     // 700   floats per (n,r)
#define RELN (RR*RELR)     // 5600  floats per n
#define KP 40          // bf16 k-stride in LDS: 80B rows -> <=2-way banks, 16B aligned
#define THALF 64       // kC t-tile (half of TT)

typedef __attribute__((ext_vector_type(8))) short short8;
typedef __attribute__((ext_vector_type(4))) float f32x4;

// portable bf16 (RNE) split helpers — bit ops only
__device__ __forceinline__ unsigned int f2bf(float f) {
    unsigned int u = __builtin_bit_cast(unsigned int, f);
    return (u + 0x7FFFu + ((u >> 16) & 1u)) >> 16;
}
__device__ __forceinline__ float bf2f(unsigned int b) {
    return __builtin_bit_cast(float, b << 16);
}

// ---------------------------------------------------------------------------
// Kernel A: xm[n,c,v] = mean over T of x[n,c,t,v].  One block per (n,c).
// (unchanged — at the BW floor)
// ---------------------------------------------------------------------------
__global__ __launch_bounds__(256) void kA_tmean(const float* __restrict__ x,
                                                float* __restrict__ xm) {
    const int blk = blockIdx.x;            // n*CC + c
    const int tid = threadIdx.x;
    __shared__ float st[TT * VV];          // 3200 floats
    __shared__ float ps[8 * VV];

    const float4* xb4 = (const float4*)(x + (size_t)blk * (TT * VV));
    float4* st4 = (float4*)st;
    for (int i = tid; i < (TT * VV) / 4; i += 256) st4[i] = xb4[i];
    __syncthreads();

    if (tid < 200) {
        const int v = tid % VV, tseg = tid / VV;   // 8 segments of 16 t
        float s = 0.f;
        const int base = tseg * 16 * VV + v;
#pragma unroll
        for (int i = 0; i < 16; i++) s += st[base + i * VV];
        ps[tseg * VV + v] = s;
    }
    __syncthreads();
    if (tid < VV) {
        float s = 0.f;
#pragma unroll
        for (int k = 0; k < 8; k++) s += ps[k * VV + tid];
        xm[(size_t)blk * VV + tid] = s * (1.f / TT);
    }
}

// ---------------------------------------------------------------------------
// Kernel B v2: parallelized 9x.
//  blocks [0, NN*RR):      (n,r) -> rel[n][r][u][28]  (pad cols v>=25 = 0)
//  blocks [NN*RR, +NN):    n     -> SE attention a_out[n][v]
// Layout identical to v1 kB outputs.
// ---------------------------------------------------------------------------
__global__ __launch_bounds__(256) void kB_small(
    const float* __restrict__ xm,
    const float* __restrict__ w1, const float* __restrict__ b1,
    const float* __restrict__ w2, const float* __restrict__ b2,
    const float* __restrict__ sw1, const float* __restrict__ sb1,
    const float* __restrict__ sw2, const float* __restrict__ sb2,
    float* __restrict__ a_out, float* __restrict__ rel_out) {
    const int bid = blockIdx.x;
    const int tid = threadIdx.x;
    __shared__ float lxm[CC * VV];   // 1600
    __shared__ float l1[VV];
    __shared__ float l2[VV];
    __shared__ float lh[HH];

    if (bid < NN * RR) {
        const int n = bid >> 3;
        const int r = bid & 7;
        for (int i = tid; i < CC * VV; i += 256) lxm[i] = xm[(size_t)n * CC * VV + i];
        __syncthreads();

        if (tid < 2 * VV) {
            const int which = tid / VV;
            const int u = tid - which * VV;
            const float* w = which ? w2 : w1;
            float s = which ? b2[r] : b1[r];
            for (int c = 0; c < CC; c++) s += w[r * CC + c] * lxm[c * VV + u];
            if (which) l2[u] = s; else l1[u] = s;
        }
        __syncthreads();

        float* ro = rel_out + (size_t)n * RELN + (size_t)r * RELR;
        for (int idx = tid; idx < RELR; idx += 256) {     // 700 -> ~3/thread
            int u = idx / RELP, v = idx - u * RELP;
            ro[idx] = (v < VV) ? tanhf(l1[u] - l2[v]) : 0.f;
        }
    } else {
        const int n = bid - NN * RR;
        for (int i = tid; i < CC * VV; i += 256) lxm[i] = xm[(size_t)n * CC * VV + i];
        __syncthreads();

        if (tid < VV) {
            float s = 0.f;
            for (int c = 0; c < CC; c++) s += lxm[c * VV + tid];
            l1[tid] = s * (1.f / CC);      // ls
        }
        __syncthreads();
        if (tid < HH) {
            float h = sb1[tid];
            for (int v = 0; v < VV; v++) h += sw1[tid * VV + v] * l1[v];
            lh[tid] = fmaxf(h, 0.f);
        }
        __syncthreads();
        if (tid < VV) {
            float z = sb2[tid];
            for (int j = 0; j < HH; j++) z += sw2[tid * HH + j] * lh[j];
            a_out[(size_t)n * VV + tid] = 1.f / (1.f + expf(-z));
        }
    }
}

// ---------------------------------------------------------------------------
// Kernel C v6 (occupancy): one block per (n,c,half) — 64-row t-tile.
//  Ad'[u,v] = (b4[c] + A[u,v] + sum_r w4[c,r]*rel[n,r,u,v]) * a[n,v]
//  out[t,u] = sum_v Ad'[u,v] * x[n,c,t,v]
// MFMA phase 2 (split-bf16: xh*adh + xh*adl + xl*adh), per-block path
// halved vs v5; LDS 15.4 KB; __launch_bounds__(256,4) caps VGPR<=128 so
// >=4 blocks/CU co-resident. ad recomputed per half (rel re-reads are L2).
// ---------------------------------------------------------------------------
__global__ __launch_bounds__(256, 4) void kC_main(
    const float* __restrict__ x, const float* __restrict__ A,
    const float* __restrict__ w4, const float* __restrict__ b4,
    const float* __restrict__ rel, const float* __restrict__ av,
    float* __restrict__ out) {
    const int bid = blockIdx.x;        // (n*CC + c)*2 + half
    const int nc = bid >> 1;
    const int half = bid & 1;
    const int n = nc >> 6;
    const int c = nc & (CC - 1);
    const int tid = threadIdx.x;

    __shared__ __align__(16) unsigned short xsb[2][THALF * KP];  // hi, lo: 2*5120 shorts
    __shared__ __align__(16) unsigned short adb[2][32 * KP];     // hi, lo
    float* os = (float*)&xsb[0][0];    // 6400 B output staging overlays xsb (10240 B)

    const float* xg = x + ((size_t)nc * TT + half * THALF) * VV;

    // --- phase 1b: stage x (64 rows) as bf16 hi/lo [t][KP], packed u32 ---
    for (int idx = tid; idx < THALF * 13; idx += 256) {   // 832 units
        const int t = idx / 13;
        const int p = idx - t * 13;
        const float* row = xg + t * VV + 2 * p;
        float f0 = row[0];
        float f1 = row[(p < 12) ? 1 : 0];   // in-bounds read
        if (p >= 12) f1 = 0.f;              // v=25 k-pad
        unsigned int h0 = f2bf(f0);
        unsigned int l0 = f2bf(f0 - bf2f(h0));
        unsigned int h1 = f2bf(f1);
        unsigned int l1 = f2bf(f1 - bf2f(h1));
        *(unsigned int*)&xsb[0][t * KP + 2 * p] = h0 | (h1 << 16);
        *(unsigned int*)&xsb[1][t * KP + 2 * p] = l0 | (l1 << 16);
    }
    // k-pad v=26..31 -> zero (uint cols 13,14,15); 192 writes, single pass
    if (tid < THALF * 3) {
        int tt = tid / 3, q = tid - (tid / 3) * 3;
        *(unsigned int*)&xsb[0][tt * KP + 26 + 2 * q] = 0u;
        *(unsigned int*)&xsb[1][tt * KP + 26 + 2 * q] = 0u;
    }

    // --- phase 1: Ad' quads -> bf16 hi/lo in adb. 175 threads = 25u x 7vq ---
    {
        float w4r[RR];
#pragma unroll
        for (int r = 0; r < RR; r++) w4r[r] = w4[c * RR + r];
        const float b4c = b4[c];

        if (tid < VV * 7) {
            const int u = tid / 7;
            const int v0 = (tid - u * 7) * 4;
            const float* rp = rel + (size_t)n * RELN + u * RELP + v0;
            float s0 = b4c, s1 = b4c, s2 = b4c, s3 = b4c;
#pragma unroll
            for (int r = 0; r < RR; r++) {
                const float4 rq = *(const float4*)(rp + r * RELR);
                s0 += w4r[r] * rq.x;
                s1 += w4r[r] * rq.y;
                s2 += w4r[r] * rq.z;
                s3 += w4r[r] * rq.w;
            }
            // clamp A/av col index for the v0=24 quad's pad lanes; those land
            // in k-cols 25..27 whose x-side is zero -> no contribution.
            const int c0 = v0;
            const int c1 = min(v0 + 1, VV - 1);
            const int c2 = min(v0 + 2, VV - 1);
            const int c3 = min(v0 + 3, VV - 1);
            const float* Ar = A + u * VV;
            const float* avp = av + (size_t)n * VV;
            float o0 = (s0 + Ar[c0]) * avp[c0];
            float o1 = (s1 + Ar[c1]) * avp[c1];
            float o2 = (s2 + Ar[c2]) * avp[c2];
            float o3 = (s3 + Ar[c3]) * avp[c3];
            unsigned int h0 = f2bf(o0), h1 = f2bf(o1), h2 = f2bf(o2), h3 = f2bf(o3);
            unsigned int l0 = f2bf(o0 - bf2f(h0));
            unsigned int l1 = f2bf(o1 - bf2f(h1));
            unsigned int l2 = f2bf(o2 - bf2f(h2));
            unsigned int l3 = f2bf(o3 - bf2f(h3));
            *(unsigned int*)&adb[0][u * KP + v0]     = h0 | (h1 << 16);
            *(unsigned int*)&adb[0][u * KP + v0 + 2] = h2 | (h3 << 16);
            *(unsigned int*)&adb[1][u * KP + v0]     = l0 | (l1 << 16);
            *(unsigned int*)&adb[1][u * KP + v0 + 2] = l2 | (l3 << 16);
        }
        // zero the never-written k-tail of real rows u=0..24 (shorts 28..39);
        // MFMA reads k=28..31 -> stale bf16 Inf/NaN would poison 0*garbage.
        if (tid < 25 * 6) {
            int u = tid / 6, q = tid - (tid / 6) * 6;
            *(unsigned int*)&adb[0][u * KP + 28 + 2 * q] = 0u;
            *(unsigned int*)&adb[1][u * KP + 28 + 2 * q] = 0u;
        }
        // n-pad rows u=25..31 -> zero
        if (tid < 7 * 20) {
            int rr2 = tid / 20, cc2 = tid - (tid / 20) * 20;
            *(unsigned int*)&adb[0][(VV + rr2) * KP + 2 * cc2] = 0u;
            *(unsigned int*)&adb[1][(VV + rr2) * KP + 2 * cc2] = 0u;
        }
    }
    __syncthreads();

    // --- phase 2: MFMA. M=64 (4 m-tiles), N=32 (2 n-tiles), K=32.
    // wave w: n-tile (w&1), m-tiles {2*(w>>1), +1}; 3 split passes each.
    const int wid = tid >> 6;
    const int lane = tid & 63;
    const int fr = lane & 15;          // fragment row (m for A, n for B)
    const int fk = (lane >> 4) * 8;    // k offset of this lane's 8 elements
    const int ni = wid & 1;
    const int mb = (wid >> 1) * 2;

    const short8 bh = *(const short8*)&adb[0][(ni * 16 + fr) * KP + fk];
    const short8 bl = *(const short8*)&adb[1][(ni * 16 + fr) * KP + fk];
    f32x4 acc[2] = {};
#pragma unroll
    for (int mi = 0; mi < 2; ++mi) {
        const int m = (mb + mi) * 16 + fr;
        const short8 ah = *(const short8*)&xsb[0][m * KP + fk];
        const short8 al = *(const short8*)&xsb[1][m * KP + fk];
        acc[mi] = __builtin_amdgcn_mfma_f32_16x16x32_bf16(ah, bh, acc[mi], 0, 0, 0);
        acc[mi] = __builtin_amdgcn_mfma_f32_16x16x32_bf16(ah, bl, acc[mi], 0, 0, 0);
        acc[mi] = __builtin_amdgcn_mfma_f32_16x16x32_bf16(al, bh, acc[mi], 0, 0, 0);
    }
    __syncthreads();   // all xsb/adb reads done; safe to overwrite with os

    // --- epilogue a: acc -> os, exact output-tile layout [t_local][25] ---
    // D mapping: col u = ni*16 + (lane&15), row t = (mb+mi)*16 + (lane>>4)*4 + r
    {
        const int u = ni * 16 + fr;
        if (u < VV) {
#pragma unroll
            for (int mi = 0; mi < 2; ++mi) {
                const int tb = (mb + mi) * 16 + (lane >> 4) * 4;
#pragma unroll
                for (int r = 0; r < 4; ++r)
                    os[(tb + r) * VV + u] = acc[mi][r];
            }
        }
    }
    __syncthreads();

    // --- epilogue b: coalesced float4 stores of the 6.4 KB tile (400 q) ---
    float4* ob4 = (float4*)(out + ((size_t)nc * TT + half * THALF) * VV);
    const float4* os4 = (const float4*)os;
    ob4[tid] = os4[tid];
    if (tid < 144) ob4[tid + 256] = os4[tid + 256];
}

// ---------------------------------------------------------------------------
extern "C" void kernel_launch(void* const* d_in, const int* in_sizes, int n_in,
                              void* d_out, int out_size, void* d_ws, size_t ws_size,
                              hipStream_t stream) {
    const float* x   = (const float*)d_in[0];
    const float* A   = (const float*)d_in[1];
    const float* w1  = (const float*)d_in[2];
    const float* b1  = (const float*)d_in[3];
    const float* w2  = (const float*)d_in[4];
    const float* b2  = (const float*)d_in[5];
    const float* w4  = (const float*)d_in[6];
    const float* b4  = (const float*)d_in[7];
    const float* sw1 = (const float*)d_in[8];
    const float* sb1 = (const float*)d_in[9];
    const float* sw2 = (const float*)d_in[10];
    const float* sb2 = (const float*)d_in[11];
    float* out = (float*)d_out;

    float* ws = (float*)d_ws;
    float* xm  = ws;                                 // N*C*V      = 204800
    float* a_s = xm + (size_t)NN * CC * VV;          // N*V        = 3200
    float* rel = a_s + (size_t)NN * VV;              // N*R*V*28   = 716800

    kA_tmean<<<NN * CC, 256, 0, stream>>>(x, xm);
    kB_small<<<NN * RR + NN, 256, 0, stream>>>(xm, w1, b1, w2, b2, sw1, sb1, sw2, sb2, a_s, rel);
    kC_main<<<NN * CC * 2, 256, 0, stream>>>(x, A, w4, b4, rel, a_s, out);
}

// Round 5
// 231.501 us; speedup vs baseline: 1.0234x; 1.0234x over previous
//
#include <hip/hip_runtime.h>
#include <hip/hip_bf16.h>

// Problem constants
#define NN 128
#define CC 64
#define TT 128
#define VV 25
#define RR 8
#define HH 12
#define RELP 28        // padded v-stride of rel rows (16B-aligned quads)
#define RELR (VV*RELP)     // 700   floats per (n,r)
#define RELN (RR*RELR)     // 5600  floats per n
#define KP 40          // bf16 k-stride in LDS: 80B rows -> <=2-way banks, 16B aligned

typedef __attribute__((ext_vector_type(8))) short short8;
typedef __attribute__((ext_vector_type(4))) float f32x4;

// ---------------------------------------------------------------------------
// Kernel A: xm[n,c,v] = mean over T of x[n,c,t,v].  One block per (n,c).
// (unchanged — at the BW floor)
// ---------------------------------------------------------------------------
__global__ __launch_bounds__(256) void kA_tmean(const float* __restrict__ x,
                                                float* __restrict__ xm) {
    const int blk = blockIdx.x;            // n*CC + c
    const int tid = threadIdx.x;
    __shared__ float st[TT * VV];          // 3200 floats
    __shared__ float ps[8 * VV];

    const float4* xb4 = (const float4*)(x + (size_t)blk * (TT * VV));
    float4* st4 = (float4*)st;
    for (int i = tid; i < (TT * VV) / 4; i += 256) st4[i] = xb4[i];
    __syncthreads();

    if (tid < 200) {
        const int v = tid % VV, tseg = tid / VV;   // 8 segments of 16 t
        float s = 0.f;
        const int base = tseg * 16 * VV + v;
#pragma unroll
        for (int i = 0; i < 16; i++) s += st[base + i * VV];
        ps[tseg * VV + v] = s;
    }
    __syncthreads();
    if (tid < VV) {
        float s = 0.f;
#pragma unroll
        for (int k = 0; k < 8; k++) s += ps[k * VV + tid];
        xm[(size_t)blk * VV + tid] = s * (1.f / TT);
    }
}

// ---------------------------------------------------------------------------
// Kernel B: per-n small pipeline. One block per n. rel written PADDED
// [n][r][u][28] (pad cols v>=25 = 0) so kC reads aligned float4 quads.
// (reverted to the R3 version — kB is ~2 µs, not a lever; the R4 split was
// bundled with the kC regression and is removed to keep one variable.)
// ---------------------------------------------------------------------------
__global__ __launch_bounds__(256) void kB_small(
    const float* __restrict__ xm,
    const float* __restrict__ w1, const float* __restrict__ b1,
    const float* __restrict__ w2, const float* __restrict__ b2,
    const float* __restrict__ sw1, const float* __restrict__ sb1,
    const float* __restrict__ sw2, const float* __restrict__ sb2,
    float* __restrict__ a_out, float* __restrict__ rel_out) {
    const int n = blockIdx.x;
    const int tid = threadIdx.x;
    __shared__ float lxm[CC * VV];   // 1600
    __shared__ float ls[VV];
    __shared__ float lh[HH];
    __shared__ float l1[RR * VV];
    __shared__ float l2[RR * VV];

    for (int i = tid; i < CC * VV; i += 256) lxm[i] = xm[(size_t)n * CC * VV + i];
    __syncthreads();

    if (tid < VV) {
        float s = 0.f;
        for (int c = 0; c < CC; c++) s += lxm[c * VV + tid];
        ls[tid] = s * (1.f / CC);
    }
    if (tid < RR * VV) {
        int r = tid / VV, v = tid % VV;
        float s1 = b1[r], s2 = b2[r];
        for (int c = 0; c < CC; c++) {
            float xv = lxm[c * VV + v];
            s1 += w1[r * CC + c] * xv;
            s2 += w2[r * CC + c] * xv;
        }
        l1[tid] = s1;
        l2[tid] = s2;
    }
    __syncthreads();

    if (tid < HH) {
        float h = sb1[tid];
        for (int v = 0; v < VV; v++) h += sw1[tid * VV + v] * ls[v];
        lh[tid] = fmaxf(h, 0.f);
    }
    __syncthreads();

    if (tid < VV) {
        float z = sb2[tid];
        for (int j = 0; j < HH; j++) z += sw2[tid * HH + j] * lh[j];
        a_out[(size_t)n * VV + tid] = 1.f / (1.f + expf(-z));
    }

    // padded rel: [r][u][28]; pad cols zero (finite, NaN-free for kC quads)
    for (int idx = tid; idx < RELN; idx += 256) {
        int r = idx / RELR;
        int rem = idx - r * RELR;
        int u = rem / RELP;
        int v = rem - u * RELP;
        float val = 0.f;
        if (v < VV) val = tanhf(l1[r * VV + u] - l2[r * VV + v]);
        rel_out[(size_t)n * RELN + idx] = val;
    }
}

// ---------------------------------------------------------------------------
// Kernel C v7: R3 structure (full 128-t tile, one block per (n,c)) with
// TRUNCATION-split bf16 conversion instead of RNE-split.
//  hi = f & 0xFFFF0000 (trunc bf16), lo = trunc16(f - hi); residual <= 2^-16.
//  Pair packing reuses the AND results: 9 VALU/pair vs ~24 for RNE-split.
//  out = xh*adh + xh*adl + xl*adh (dropped xl*adl ~ 2^-16).
// Everything else identical to the verified R3 kernel (layouts, MFMA, NaN-fix
// pads for adb k-tail/rows, os overlay epilogue).
// ---------------------------------------------------------------------------
__global__ __launch_bounds__(256) void kC_main(
    const float* __restrict__ x, const float* __restrict__ A,
    const float* __restrict__ w4, const float* __restrict__ b4,
    const float* __restrict__ rel, const float* __restrict__ av,
    float* __restrict__ out) {
    const int blk = blockIdx.x;    // n*CC + c
    const int n = blk >> 6;
    const int c = blk & (CC - 1);
    const int tid = threadIdx.x;

    __shared__ __align__(16) unsigned short xsb[2][TT * KP];   // hi, lo
    __shared__ __align__(16) unsigned short adb[2][32 * KP];   // hi, lo
    float* os = (float*)&xsb[0][0];   // 12800 B output staging overlays xsb (20480 B)

    const float* xg = x + (size_t)blk * (TT * VV);

    // --- phase 1b: stage x as trunc-split bf16 hi/lo, [t][KP], u32 pairs ---
    // unit idx = t*13 + p covers v-pairs (2p, 2p+1); 1664 units, 6.5/thread.
    {
        int t = tid / 13;
        int p = tid - t * 13;
#pragma unroll
        for (int it = 0; it < 7; ++it) {
            if (it < 6 || t < TT) {
                const float* row = xg + t * VV + 2 * p;
                float f0 = row[0];
                float f1 = row[(p < 12) ? 1 : 0];   // in-bounds read
                if (p >= 12) f1 = 0.f;              // v=25 k-pad -> 0
                unsigned int u0 = __builtin_bit_cast(unsigned int, f0);
                unsigned int u1 = __builtin_bit_cast(unsigned int, f1);
                unsigned int hb0 = u0 & 0xFFFF0000u;
                unsigned int hb1 = u1 & 0xFFFF0000u;
                float r0 = f0 - __builtin_bit_cast(float, hb0);
                float r1 = f1 - __builtin_bit_cast(float, hb1);
                unsigned int ru0 = __builtin_bit_cast(unsigned int, r0);
                unsigned int ru1 = __builtin_bit_cast(unsigned int, r1);
                *(unsigned int*)&xsb[0][t * KP + 2 * p] = (u0 >> 16) | hb1;
                *(unsigned int*)&xsb[1][t * KP + 2 * p] = (ru0 >> 16) | (ru1 & 0xFFFF0000u);
            }
            p += 9; t += 19;
            if (p >= 13) { p -= 13; ++t; }
        }
        // k-pad v=26..31 -> zero (uint cols 13,14,15)
        for (int i = tid; i < TT * 3; i += 256) {
            int tt = i / 3, q = i - (i / 3) * 3;
            *(unsigned int*)&xsb[0][tt * KP + 26 + 2 * q] = 0u;
            *(unsigned int*)&xsb[1][tt * KP + 26 + 2 * q] = 0u;
        }
    }

    // --- phase 1: Ad' quads -> trunc-split bf16 in adb. 175 thr = 25u x 7vq ---
    {
        float w4r[RR];
#pragma unroll
        for (int r = 0; r < RR; r++) w4r[r] = w4[c * RR + r];
        const float b4c = b4[c];

        if (tid < VV * 7) {
            const int u = tid / 7;
            const int v0 = (tid - u * 7) * 4;
            const float* rp = rel + (size_t)n * RELN + u * RELP + v0;
            float s0 = b4c, s1 = b4c, s2 = b4c, s3 = b4c;
#pragma unroll
            for (int r = 0; r < RR; r++) {
                const float4 rq = *(const float4*)(rp + r * RELR);
                s0 += w4r[r] * rq.x;
                s1 += w4r[r] * rq.y;
                s2 += w4r[r] * rq.z;
                s3 += w4r[r] * rq.w;
            }
            // clamp A/av col index for the v0=24 quad's pad lanes; those land
            // in k-cols 25..27 whose x-side is zero -> no contribution.
            const int c0 = v0;
            const int c1 = min(v0 + 1, VV - 1);
            const int c2 = min(v0 + 2, VV - 1);
            const int c3 = min(v0 + 3, VV - 1);
            const float* Ar = A + u * VV;
            const float* avp = av + (size_t)n * VV;
            float o0 = (s0 + Ar[c0]) * avp[c0];
            float o1 = (s1 + Ar[c1]) * avp[c1];
            float o2 = (s2 + Ar[c2]) * avp[c2];
            float o3 = (s3 + Ar[c3]) * avp[c3];
            unsigned int u0 = __builtin_bit_cast(unsigned int, o0);
            unsigned int u1 = __builtin_bit_cast(unsigned int, o1);
            unsigned int u2 = __builtin_bit_cast(unsigned int, o2);
            unsigned int u3 = __builtin_bit_cast(unsigned int, o3);
            unsigned int hb0 = u0 & 0xFFFF0000u, hb1 = u1 & 0xFFFF0000u;
            unsigned int hb2 = u2 & 0xFFFF0000u, hb3 = u3 & 0xFFFF0000u;
            float r0 = o0 - __builtin_bit_cast(float, hb0);
            float r1 = o1 - __builtin_bit_cast(float, hb1);
            float r2 = o2 - __builtin_bit_cast(float, hb2);
            float r3 = o3 - __builtin_bit_cast(float, hb3);
            unsigned int ru0 = __builtin_bit_cast(unsigned int, r0);
            unsigned int ru1 = __builtin_bit_cast(unsigned int, r1);
            unsigned int ru2 = __builtin_bit_cast(unsigned int, r2);
            unsigned int ru3 = __builtin_bit_cast(unsigned int, r3);
            *(unsigned int*)&adb[0][u * KP + v0]     = (u0 >> 16) | hb1;
            *(unsigned int*)&adb[0][u * KP + v0 + 2] = (u2 >> 16) | hb3;
            *(unsigned int*)&adb[1][u * KP + v0]     = (ru0 >> 16) | (ru1 & 0xFFFF0000u);
            *(unsigned int*)&adb[1][u * KP + v0 + 2] = (ru2 >> 16) | (ru3 & 0xFFFF0000u);
        }
        // zero the never-written k-tail of real rows u=0..24 (shorts 28..39);
        // MFMA reads k=28..31 -> stale bf16 Inf/NaN would poison 0*garbage.
        if (tid < 25 * 6) {
            int u = tid / 6, q = tid - (tid / 6) * 6;
            *(unsigned int*)&adb[0][u * KP + 28 + 2 * q] = 0u;
            *(unsigned int*)&adb[1][u * KP + 28 + 2 * q] = 0u;
        }
        // n-pad rows u=25..31 -> zero
        for (int i = tid; i < 7 * 20; i += 256) {
            int rr2 = i / 20, cc2 = i - (i / 20) * 20;
            *(unsigned int*)&adb[0][(VV + rr2) * KP + 2 * cc2] = 0u;
            *(unsigned int*)&adb[1][(VV + rr2) * KP + 2 * cc2] = 0u;
        }
    }
    __syncthreads();

    // --- phase 2: MFMA. M=128 (8 m-tiles), N=32 (2 n-tiles), K=32 (1 step).
    // wave w owns m-tiles {2w, 2w+1} x n-tiles {0,1}; 3 split passes.
    const int wid = tid >> 6;
    const int lane = tid & 63;
    const int fr = lane & 15;          // fragment row (m for A, n for B)
    const int fk = (lane >> 4) * 8;    // k offset of this lane's 8 elements

    f32x4 acc[2][2] = {};
    short8 ah[2], al[2], bh[2], bl[2];
#pragma unroll
    for (int mi = 0; mi < 2; ++mi) {
        const int m = (wid * 2 + mi) * 16 + fr;
        ah[mi] = *(const short8*)&xsb[0][m * KP + fk];
        al[mi] = *(const short8*)&xsb[1][m * KP + fk];
    }
#pragma unroll
    for (int ni = 0; ni < 2; ++ni) {
        const int nn2 = ni * 16 + fr;
        bh[ni] = *(const short8*)&adb[0][nn2 * KP + fk];
        bl[ni] = *(const short8*)&adb[1][nn2 * KP + fk];
    }
#pragma unroll
    for (int mi = 0; mi < 2; ++mi)
#pragma unroll
        for (int ni = 0; ni < 2; ++ni) {
            acc[mi][ni] = __builtin_amdgcn_mfma_f32_16x16x32_bf16(ah[mi], bh[ni], acc[mi][ni], 0, 0, 0);
            acc[mi][ni] = __builtin_amdgcn_mfma_f32_16x16x32_bf16(ah[mi], bl[ni], acc[mi][ni], 0, 0, 0);
            acc[mi][ni] = __builtin_amdgcn_mfma_f32_16x16x32_bf16(al[mi], bh[ni], acc[mi][ni], 0, 0, 0);
        }
    __syncthreads();   // all xsb/adb reads done; safe to overwrite with os

    // --- epilogue a: acc -> os with exact output-tile layout [t][25] ---
    // D mapping: col u = ntile*16 + (lane&15), row t = mtile*16 + (lane>>4)*4 + r
#pragma unroll
    for (int mi = 0; mi < 2; ++mi) {
        const int tb = (wid * 2 + mi) * 16 + (lane >> 4) * 4;
#pragma unroll
        for (int ni = 0; ni < 2; ++ni) {
            const int u = ni * 16 + fr;
            if (u < VV) {
#pragma unroll
                for (int r = 0; r < 4; ++r)
                    os[(tb + r) * VV + u] = acc[mi][ni][r];
            }
        }
    }
    __syncthreads();

    // --- epilogue b: coalesced float4 stores of the whole 12.8 KB tile ---
    float4* ob4 = (float4*)(out + (size_t)blk * (TT * VV));
    const float4* os4 = (const float4*)os;
    ob4[tid]       = os4[tid];
    ob4[tid + 256] = os4[tid + 256];
    ob4[tid + 512] = os4[tid + 512];
    if (tid < 32) ob4[tid + 768] = os4[tid + 768];
}

// ---------------------------------------------------------------------------
extern "C" void kernel_launch(void* const* d_in, const int* in_sizes, int n_in,
                              void* d_out, int out_size, void* d_ws, size_t ws_size,
                              hipStream_t stream) {
    const float* x   = (const float*)d_in[0];
    const float* A   = (const float*)d_in[1];
    const float* w1  = (const float*)d_in[2];
    const float* b1  = (const float*)d_in[3];
    const float* w2  = (const float*)d_in[4];
    const float* b2  = (const float*)d_in[5];
    const float* w4  = (const float*)d_in[6];
    const float* b4  = (const float*)d_in[7];
    const float* sw1 = (const float*)d_in[8];
    const float* sb1 = (const float*)d_in[9];
    const float* sw2 = (const float*)d_in[10];
    const float* sb2 = (const float*)d_in[11];
    float* out = (float*)d_out;

    float* ws = (float*)d_ws;
    float* xm  = ws;                                 // N*C*V      = 204800
    float* a_s = xm + (size_t)NN * CC * VV;          // N*V        = 3200
    float* rel = a_s + (size_t)NN * VV;              // N*R*V*28   = 716800

    kA_tmean<<<NN * CC, 256, 0, stream>>>(x, xm);
    kB_small<<<NN, 256, 0, stream>>>(xm, w1, b1, w2, b2, sw1, sb1, sw2, sb2, a_s, rel);
    kC_main<<<NN * CC, 256, 0, stream>>>(x, A, w4, b4, rel, a_s, out);
}

// Round 7
// 230.500 us; speedup vs baseline: 1.0279x; 1.0043x over previous
//
#include <hip/hip_runtime.h>
#include <hip/hip_bf16.h>

// Problem constants
#define NN 128
#define CC 64
#define TT 128
#define VV 25
#define RR 8
#define HH 12
#define RELP 28        // padded v-stride of rel rows (16B-aligned quads)
#define RELR (VV*RELP)     // 700   floats per (n,r)
#define RELN (RR*RELR)     // 5600  floats per n
#define KP 40          // bf16 k-stride in adb LDS: 80B rows, 16B-aligned frags

typedef __attribute__((ext_vector_type(8))) short short8;
typedef __attribute__((ext_vector_type(4))) float f32x4;
typedef __attribute__((ext_vector_type(4))) unsigned int u32x4;

// unaligned-safe 8-float load (row stride 25 -> only 4B alignment guaranteed)
__device__ __forceinline__ void loadu8(const float* p, f32x4& a, f32x4& b) {
    __builtin_memcpy(&a, p, 16);
    __builtin_memcpy(&b, p + 4, 16);
}

// trunc-split 8 floats -> bf16 hi/lo short8 frags (hi = f&0xFFFF0000)
__device__ __forceinline__ void cvt8(const f32x4& a, const f32x4& b,
                                     short8& hi, short8& lo) {
    float f[8] = {a.x, a.y, a.z, a.w, b.x, b.y, b.z, b.w};
    unsigned int u[8], r[8];
#pragma unroll
    for (int j = 0; j < 8; j++) u[j] = __builtin_bit_cast(unsigned int, f[j]);
#pragma unroll
    for (int j = 0; j < 8; j++)
        r[j] = __builtin_bit_cast(unsigned int,
                 f[j] - __builtin_bit_cast(float, u[j] & 0xFFFF0000u));
    u32x4 H = { (u[0] >> 16) | (u[1] & 0xFFFF0000u),
                (u[2] >> 16) | (u[3] & 0xFFFF0000u),
                (u[4] >> 16) | (u[5] & 0xFFFF0000u),
                (u[6] >> 16) | (u[7] & 0xFFFF0000u) };
    u32x4 L = { (r[0] >> 16) | (r[1] & 0xFFFF0000u),
                (r[2] >> 16) | (r[3] & 0xFFFF0000u),
                (r[4] >> 16) | (r[5] & 0xFFFF0000u),
                (r[6] >> 16) | (r[7] & 0xFFFF0000u) };
    hi = __builtin_bit_cast(short8, H);
    lo = __builtin_bit_cast(short8, L);
}

// single real element (v=24) + 7 zero k-pad
__device__ __forceinline__ void cvt1(float s, short8& hi, short8& lo) {
    unsigned int us = __builtin_bit_cast(unsigned int, s);
    float rs = s - __builtin_bit_cast(float, us & 0xFFFF0000u);
    u32x4 H = { us >> 16, 0u, 0u, 0u };
    u32x4 L = { __builtin_bit_cast(unsigned int, rs) >> 16, 0u, 0u, 0u };
    hi = __builtin_bit_cast(short8, H);
    lo = __builtin_bit_cast(short8, L);
}

// ---------------------------------------------------------------------------
// Kernel A: xm[n,c,v] = mean over T of x[n,c,t,v].  One block per (n,c).
// (unchanged)
// ---------------------------------------------------------------------------
__global__ __launch_bounds__(256) void kA_tmean(const float* __restrict__ x,
                                                float* __restrict__ xm) {
    const int blk = blockIdx.x;            // n*CC + c
    const int tid = threadIdx.x;
    __shared__ float st[TT * VV];          // 3200 floats
    __shared__ float ps[8 * VV];

    const float4* xb4 = (const float4*)(x + (size_t)blk * (TT * VV));
    float4* st4 = (float4*)st;
    for (int i = tid; i < (TT * VV) / 4; i += 256) st4[i] = xb4[i];
    __syncthreads();

    if (tid < 200) {
        const int v = tid % VV, tseg = tid / VV;   // 8 segments of 16 t
        float s = 0.f;
        const int base = tseg * 16 * VV + v;
#pragma unroll
        for (int i = 0; i < 16; i++) s += st[base + i * VV];
        ps[tseg * VV + v] = s;
    }
    __syncthreads();
    if (tid < VV) {
        float s = 0.f;
#pragma unroll
        for (int k = 0; k < 8; k++) s += ps[k * VV + tid];
        xm[(size_t)blk * VV + tid] = s * (1.f / TT);
    }
}

// ---------------------------------------------------------------------------
// Kernel B: per-n small pipeline. One block per n. rel written PADDED
// [n][r][u][28] (pad cols v>=25 = 0). (unchanged)
// ---------------------------------------------------------------------------
__global__ __launch_bounds__(256) void kB_small(
    const float* __restrict__ xm,
    const float* __restrict__ w1, const float* __restrict__ b1,
    const float* __restrict__ w2, const float* __restrict__ b2,
    const float* __restrict__ sw1, const float* __restrict__ sb1,
    const float* __restrict__ sw2, const float* __restrict__ sb2,
    float* __restrict__ a_out, float* __restrict__ rel_out) {
    const int n = blockIdx.x;
    const int tid = threadIdx.x;
    __shared__ float lxm[CC * VV];   // 1600
    __shared__ float ls[VV];
    __shared__ float lh[HH];
    __shared__ float l1[RR * VV];
    __shared__ float l2[RR * VV];

    for (int i = tid; i < CC * VV; i += 256) lxm[i] = xm[(size_t)n * CC * VV + i];
    __syncthreads();

    if (tid < VV) {
        float s = 0.f;
        for (int c = 0; c < CC; c++) s += lxm[c * VV + tid];
        ls[tid] = s * (1.f / CC);
    }
    if (tid < RR * VV) {
        int r = tid / VV, v = tid % VV;
        float s1 = b1[r], s2 = b2[r];
        for (int c = 0; c < CC; c++) {
            float xv = lxm[c * VV + v];
            s1 += w1[r * CC + c] * xv;
            s2 += w2[r * CC + c] * xv;
        }
        l1[tid] = s1;
        l2[tid] = s2;
    }
    __syncthreads();

    if (tid < HH) {
        float h = sb1[tid];
        for (int v = 0; v < VV; v++) h += sw1[tid * VV + v] * ls[v];
        lh[tid] = fmaxf(h, 0.f);
    }
    __syncthreads();

    if (tid < VV) {
        float z = sb2[tid];
        for (int j = 0; j < HH; j++) z += sw2[tid * HH + j] * lh[j];
        a_out[(size_t)n * VV + tid] = 1.f / (1.f + expf(-z));
    }

    // padded rel: [r][u][28]; pad cols zero (finite, NaN-free for kC quads)
    for (int idx = tid; idx < RELN; idx += 256) {
        int r = idx / RELR;
        int rem = idx - r * RELR;
        int u = rem / RELP;
        int v = rem - u * RELP;
        float val = 0.f;
        if (v < VV) val = tanhf(l1[r * VV + u] - l2[r * VV + v]);
        rel_out[(size_t)n * RELN + idx] = val;
    }
}

// ---------------------------------------------------------------------------
// Kernel C v8 (no x-staging; NT-store type fix):
//  Ad'[u,v] = (b4[c] + A[u,v] + sum_r w4[c,r]*rel[n,r,u,v]) * a[n,v]
//  out[t,u] = sum_v Ad'[u,v] * x[n,c,t,v]
// MFMA A-fragments load DIRECTLY from global x (hoisted to kernel entry so
// the latency hides under the ad phase) and trunc-split in-register.
// Removes per thread ~14 scalar loads + ~14 ds_writes + xsb buffer + 2
// barriers vs v7. LDS: adb 5 KB + os 12.8 KB = 17.9 KB. out stores are
// nontemporal via native ext-vector f32x4 (__builtin_nontemporal_store
// rejects HIP_vector_type float4 — R6 compile fix).
// Split numerics identical to verified v7 (out = xh*adh + xh*adl + xl*adh).
// ---------------------------------------------------------------------------
__global__ __launch_bounds__(256) void kC_main(
    const float* __restrict__ x, const float* __restrict__ A,
    const float* __restrict__ w4, const float* __restrict__ b4,
    const float* __restrict__ rel, const float* __restrict__ av,
    float* __restrict__ out) {
    const int blk = blockIdx.x;    // n*CC + c
    const int n = blk >> 6;
    const int c = blk & (CC - 1);
    const int tid = threadIdx.x;

    __shared__ __align__(16) unsigned short adb[2][32 * KP];   // hi, lo (5120 B)
    __shared__ __align__(16) float os[TT * VV];                // 12800 B

    const float* xg = x + (size_t)blk * (TT * VV);

    // --- hoisted A-fragment global loads (latency hides under ad phase) ---
    const int wid = tid >> 6;
    const int lane = tid & 63;
    const int fr = lane & 15;          // fragment row (m for A, n for B)
    const int fkq = lane >> 4;         // k-quarter 0..3
    const int fk = fkq * 8;            // k offset of this lane's 8 elements
    const int m0 = (wid * 2 + 0) * 16 + fr;
    const int m1 = (wid * 2 + 1) * 16 + fr;

    f32x4 qa00, qa01, qa10, qa11;
    float qs0 = 0.f, qs1 = 0.f;
    if (fkq < 3) {
        // k = fk..fk+7 (v <= 23), all in-tile: max dword 127*25+23 = 3198
        loadu8(xg + m0 * VV + fk, qa00, qa01);
        loadu8(xg + m1 * VV + fk, qa10, qa11);
    } else {
        // k-quarter 3: only v=24 is real; v=25..31 zero k-pad
        qs0 = xg[m0 * VV + 24];
        qs1 = xg[m1 * VV + 24];
    }

    // --- phase 1: Ad' quads -> trunc-split bf16 in adb. 175 thr = 25u x 7vq ---
    {
        float w4r[RR];
#pragma unroll
        for (int r = 0; r < RR; r++) w4r[r] = w4[c * RR + r];
        const float b4c = b4[c];

        if (tid < VV * 7) {
            const int u = tid / 7;
            const int v0 = (tid - u * 7) * 4;
            const float* rp = rel + (size_t)n * RELN + u * RELP + v0;
            float s0 = b4c, s1 = b4c, s2 = b4c, s3 = b4c;
#pragma unroll
            for (int r = 0; r < RR; r++) {
                const float4 rq = *(const float4*)(rp + r * RELR);
                s0 += w4r[r] * rq.x;
                s1 += w4r[r] * rq.y;
                s2 += w4r[r] * rq.z;
                s3 += w4r[r] * rq.w;
            }
            // clamp A/av col index for the v0=24 quad's pad lanes; those land
            // in k-cols 25..27 whose x-side is zero -> no contribution.
            const int c0 = v0;
            const int c1 = min(v0 + 1, VV - 1);
            const int c2 = min(v0 + 2, VV - 1);
            const int c3 = min(v0 + 3, VV - 1);
            const float* Ar = A + u * VV;
            const float* avp = av + (size_t)n * VV;
            float o0 = (s0 + Ar[c0]) * avp[c0];
            float o1 = (s1 + Ar[c1]) * avp[c1];
            float o2 = (s2 + Ar[c2]) * avp[c2];
            float o3 = (s3 + Ar[c3]) * avp[c3];
            unsigned int u0 = __builtin_bit_cast(unsigned int, o0);
            unsigned int u1 = __builtin_bit_cast(unsigned int, o1);
            unsigned int u2 = __builtin_bit_cast(unsigned int, o2);
            unsigned int u3 = __builtin_bit_cast(unsigned int, o3);
            unsigned int hb0 = u0 & 0xFFFF0000u, hb1 = u1 & 0xFFFF0000u;
            unsigned int hb2 = u2 & 0xFFFF0000u, hb3 = u3 & 0xFFFF0000u;
            float r0 = o0 - __builtin_bit_cast(float, hb0);
            float r1 = o1 - __builtin_bit_cast(float, hb1);
            float r2 = o2 - __builtin_bit_cast(float, hb2);
            float r3 = o3 - __builtin_bit_cast(float, hb3);
            unsigned int ru0 = __builtin_bit_cast(unsigned int, r0);
            unsigned int ru1 = __builtin_bit_cast(unsigned int, r1);
            unsigned int ru2 = __builtin_bit_cast(unsigned int, r2);
            unsigned int ru3 = __builtin_bit_cast(unsigned int, r3);
            *(unsigned int*)&adb[0][u * KP + v0]     = (u0 >> 16) | hb1;
            *(unsigned int*)&adb[0][u * KP + v0 + 2] = (u2 >> 16) | hb3;
            *(unsigned int*)&adb[1][u * KP + v0]     = (ru0 >> 16) | (ru1 & 0xFFFF0000u);
            *(unsigned int*)&adb[1][u * KP + v0 + 2] = (ru2 >> 16) | (ru3 & 0xFFFF0000u);
        }
        // zero the never-written k-tail of real rows u=0..24 (shorts 28..39);
        // MFMA reads k=28..31 -> stale bf16 Inf/NaN would make 0*garbage=NaN.
        if (tid < 25 * 6) {
            int u = tid / 6, q = tid - (tid / 6) * 6;
            *(unsigned int*)&adb[0][u * KP + 28 + 2 * q] = 0u;
            *(unsigned int*)&adb[1][u * KP + 28 + 2 * q] = 0u;
        }
        // n-pad rows u=25..31 -> zero
        if (tid < 7 * 20) {
            int rr2 = tid / 20, cc2 = tid - (tid / 20) * 20;
            *(unsigned int*)&adb[0][(VV + rr2) * KP + 2 * cc2] = 0u;
            *(unsigned int*)&adb[1][(VV + rr2) * KP + 2 * cc2] = 0u;
        }
    }
    __syncthreads();   // adb ready

    // --- phase 2: build A frags in-register, read B frags, 12 MFMA ---
    short8 ah0, al0, ah1, al1;
    if (fkq < 3) {
        cvt8(qa00, qa01, ah0, al0);
        cvt8(qa10, qa11, ah1, al1);
    } else {
        cvt1(qs0, ah0, al0);
        cvt1(qs1, ah1, al1);
    }
    short8 bh[2], bl[2];
#pragma unroll
    for (int ni = 0; ni < 2; ++ni) {
        const int nn2 = ni * 16 + fr;
        bh[ni] = *(const short8*)&adb[0][nn2 * KP + fk];
        bl[ni] = *(const short8*)&adb[1][nn2 * KP + fk];
    }
    f32x4 acc[2][2] = {};
#pragma unroll
    for (int ni = 0; ni < 2; ++ni) {
        acc[0][ni] = __builtin_amdgcn_mfma_f32_16x16x32_bf16(ah0, bh[ni], acc[0][ni], 0, 0, 0);
        acc[0][ni] = __builtin_amdgcn_mfma_f32_16x16x32_bf16(ah0, bl[ni], acc[0][ni], 0, 0, 0);
        acc[0][ni] = __builtin_amdgcn_mfma_f32_16x16x32_bf16(al0, bh[ni], acc[0][ni], 0, 0, 0);
        acc[1][ni] = __builtin_amdgcn_mfma_f32_16x16x32_bf16(ah1, bh[ni], acc[1][ni], 0, 0, 0);
        acc[1][ni] = __builtin_amdgcn_mfma_f32_16x16x32_bf16(ah1, bl[ni], acc[1][ni], 0, 0, 0);
        acc[1][ni] = __builtin_amdgcn_mfma_f32_16x16x32_bf16(al1, bh[ni], acc[1][ni], 0, 0, 0);
    }

    // --- epilogue a: acc -> os with exact output-tile layout [t][25] ---
    // D mapping: col u = ntile*16 + (lane&15), row t = mtile*16 + (lane>>4)*4 + r
#pragma unroll
    for (int mi = 0; mi < 2; ++mi) {
        const int tb = (wid * 2 + mi) * 16 + fkq * 4;
#pragma unroll
        for (int ni = 0; ni < 2; ++ni) {
            const int u = ni * 16 + fr;
            if (u < VV) {
#pragma unroll
                for (int r = 0; r < 4; ++r)
                    os[(tb + r) * VV + u] = acc[mi][ni][r];
            }
        }
    }
    __syncthreads();

    // --- epilogue b: coalesced nontemporal stores via native ext-vector ---
    f32x4* ob4 = (f32x4*)(out + (size_t)blk * (TT * VV));
    const f32x4* os4 = (const f32x4*)os;
    __builtin_nontemporal_store(os4[tid],       &ob4[tid]);
    __builtin_nontemporal_store(os4[tid + 256], &ob4[tid + 256]);
    __builtin_nontemporal_store(os4[tid + 512], &ob4[tid + 512]);
    if (tid < 32) __builtin_nontemporal_store(os4[tid + 768], &ob4[tid + 768]);
}

// ---------------------------------------------------------------------------
extern "C" void kernel_launch(void* const* d_in, const int* in_sizes, int n_in,
                              void* d_out, int out_size, void* d_ws, size_t ws_size,
                              hipStream_t stream) {
    const float* x   = (const float*)d_in[0];
    const float* A   = (const float*)d_in[1];
    const float* w1  = (const float*)d_in[2];
    const float* b1  = (const float*)d_in[3];
    const float* w2  = (const float*)d_in[4];
    const float* b2  = (const float*)d_in[5];
    const float* w4  = (const float*)d_in[6];
    const float* b4  = (const float*)d_in[7];
    const float* sw1 = (const float*)d_in[8];
    const float* sb1 = (const float*)d_in[9];
    const float* sw2 = (const float*)d_in[10];
    const float* sb2 = (const float*)d_in[11];
    float* out = (float*)d_out;

    float* ws = (float*)d_ws;
    float* xm  = ws;                                 // N*C*V      = 204800
    float* a_s = xm + (size_t)NN * CC * VV;          // N*V        = 3200
    float* rel = a_s + (size_t)NN * VV;              // N*R*V*28   = 716800

    kA_tmean<<<NN * CC, 256, 0, stream>>>(x, xm);
    kB_small<<<NN, 256, 0, stream>>>(xm, w1, b1, w2, b2, sw1, sb1, sw2, sb2, a_s, rel);
    kC_main<<<NN * CC, 256, 0, stream>>>(x, A, w4, b4, rel, a_s, out);
}